// Round 1
// baseline (4896.341 us; speedup 1.0000x reference)
//
#include <hip/hip_runtime.h>
#include <math.h>

#define BLROWS 32000   // B*L = 32*1000
#define LSEQ   1000
#define NBATCH 32

__device__ __forceinline__ float sigmoidf_(float x){ return 1.f/(1.f+__expf(-x)); }

// ---------------- input projection: h = x @ inp_w.T + inp_b ----------------
// x: [BL,12], inp_w: [128,12], h: [BL,128]
__global__ __launch_bounds__(256) void k_inproj(const float* __restrict__ x,
    const float* __restrict__ w, const float* __restrict__ bias, float* __restrict__ h){
  int idx = blockIdx.x*256 + threadIdx.x;    // r*128 + c
  int r = idx >> 7, c = idx & 127;
  const float* xr = x + (long)r*12;
  const float* wr = w + c*12;
  float acc = bias[c];
  #pragma unroll
  for (int k=0;k<12;k++) acc = fmaf(xr[k], wr[k], acc);
  h[idx] = acc;
}

// ---------------- layernorm: one wave per row of 128 ----------------
__global__ __launch_bounds__(256) void k_ln(const float* __restrict__ h,
    const float* __restrict__ w, const float* __restrict__ b, float* __restrict__ out){
  int wv = threadIdx.x >> 6, lane = threadIdx.x & 63;
  long r = (long)blockIdx.x*4 + wv;
  float2 v = ((const float2*)(h + r*128))[lane];
  float s = v.x + v.y;
  #pragma unroll
  for (int m=32;m>=1;m>>=1) s += __shfl_xor(s, m);
  float mu = s * (1.f/128.f);
  float dx = v.x - mu, dy = v.y - mu;
  float q = dx*dx + dy*dy;
  #pragma unroll
  for (int m=32;m>=1;m>>=1) q += __shfl_xor(q, m);
  float rstd = rsqrtf(q*(1.f/128.f) + 1e-5f);
  float2 wvv = ((const float2*)w)[lane];
  float2 bvv = ((const float2*)b)[lane];
  float2 o; o.x = dx*rstd*wvv.x + bvv.x; o.y = dy*rstd*wvv.y + bvv.y;
  ((float2*)(out + r*128))[lane] = o;
}

// ---------------- GEMM1: xz[BL,512] = n[BL,128] @ W[512,128]^T ----------------
// block: 256 thr, 16 rows, 2 cols/thread. A tile in LDS (broadcast reads), W streams via L2.
__global__ __launch_bounds__(256) void k_gemm_xz(const float* __restrict__ n,
    const float* __restrict__ W, float* __restrict__ xz){
  __shared__ float4 As[16][32];     // 16 rows x 128 floats
  int tid = threadIdx.x;
  long r0 = (long)blockIdx.x * 16;
  const float4* src = (const float4*)(n + r0*128);
  ((float4*)As)[tid]     = src[tid];
  ((float4*)As)[tid+256] = src[tid+256];
  __syncthreads();
  const float4* w0 = (const float4*)(W + (long)tid*128);
  const float4* w1 = (const float4*)(W + (long)(tid+256)*128);
  float acc0[16], acc1[16];
  #pragma unroll
  for (int r=0;r<16;r++){ acc0[r]=0.f; acc1[r]=0.f; }
  for (int k=0;k<32;k++){
    float4 a = w0[k], c = w1[k];
    #pragma unroll
    for (int r=0;r<16;r++){
      float4 av = As[r][k];
      acc0[r] = fmaf(av.x,a.x,fmaf(av.y,a.y,fmaf(av.z,a.z,fmaf(av.w,a.w,acc0[r]))));
      acc1[r] = fmaf(av.x,c.x,fmaf(av.y,c.y,fmaf(av.z,c.z,fmaf(av.w,c.w,acc1[r]))));
    }
  }
  float* orow = xz + r0*512;
  #pragma unroll
  for (int r=0;r<16;r++){
    orow[(long)r*512 + tid]       = acc0[r];
    orow[(long)r*512 + tid + 256] = acc1[r];
  }
}

// ---------------- causal depthwise conv (K=4) + SiLU ----------------
// u_pre = xz[:, 0:256]; u[r,d] = silu(sum_j xz[r-j, d] * w[d, 3-j] + b[d])
__global__ __launch_bounds__(256) void k_conv(const float* __restrict__ xz,
    const float* __restrict__ cw, const float* __restrict__ cb, float* __restrict__ u){
  long r = blockIdx.x; int d = threadIdx.x;
  int t = (int)(r % 1000);
  float w0=cw[d*4+0], w1=cw[d*4+1], w2=cw[d*4+2], w3=cw[d*4+3];
  const float* base = xz + r*512 + d;
  float acc = cb[d] + base[0]*w3;
  if (t>=1) acc = fmaf(base[-512],  w2, acc);
  if (t>=2) acc = fmaf(base[-1024], w1, acc);
  if (t>=3) acc = fmaf(base[-1536], w0, acc);
  u[r*256 + d] = acc * sigmoidf_(acc);
}

// ---------------- GEMM2: x_dbl[BL,40] = u[BL,256] @ xp_w[40,256]^T ----------------
// block: 256 thr = 4 groups x 64 cols (40 active), 8 rows per group, 32 rows/block
__global__ __launch_bounds__(256) void k_gemm_xdbl(const float* __restrict__ u,
    const float* __restrict__ W, float* __restrict__ xd){
  __shared__ float4 As[32][64];    // 32 KB
  int tid = threadIdx.x;
  long r0 = (long)blockIdx.x * 32;
  const float4* src = (const float4*)(u + r0*256);
  #pragma unroll
  for (int j=0;j<8;j++) ((float4*)As)[tid + j*256] = src[tid + j*256];
  __syncthreads();
  int g = tid >> 6, c = tid & 63;
  int ce = c < 40 ? c : 39;
  const float4* w = (const float4*)(W + (long)ce*256);
  float acc[8];
  #pragma unroll
  for (int r=0;r<8;r++) acc[r]=0.f;
  for (int k=0;k<64;k++){
    float4 wv = w[k];
    #pragma unroll
    for (int r=0;r<8;r++){
      float4 av = As[g*8+r][k];
      acc[r] = fmaf(av.x,wv.x,fmaf(av.y,wv.y,fmaf(av.z,wv.z,fmaf(av.w,wv.w,acc[r]))));
    }
  }
  if (c < 40){
    #pragma unroll
    for (int r=0;r<8;r++) xd[(r0 + g*8 + r)*40 + c] = acc[r];
  }
}

// ---------------- fused dt-proj + softplus + selective scan + gating ----------------
// grid: 32 b x 4 dgroups; block: 64 (one wave). Each thread owns channel d, 16-wide state in regs.
__global__ __launch_bounds__(64) void k_scan(const float* __restrict__ xz,
    const float* __restrict__ u, const float* __restrict__ xd,
    const float* __restrict__ dtw, const float* __restrict__ dtb,
    const float* __restrict__ alog, const float* __restrict__ Dp,
    float* __restrict__ y){
  int b = blockIdx.x >> 2, dg = blockIdx.x & 3;
  int lane = threadIdx.x;
  int d = dg*64 + lane;
  float a[16], hst[16];
  #pragma unroll
  for (int s=0;s<16;s++){ a[s] = -__expf(alog[d*16+s]); hst[s]=0.f; }
  float wdt[8];
  #pragma unroll
  for (int j=0;j<8;j++) wdt[j] = dtw[d*8+j];
  float bias = dtb[d], Dpd = Dp[d];
  __shared__ float sxd[320];   // 8 timesteps x 40 (dt_pre 8 | B 16 | C 16)
  for (int tc=0; tc<125; tc++){
    long r0 = (long)b*1000 + tc*8;
    const float* src = xd + r0*40;
    #pragma unroll
    for (int j=0;j<5;j++) sxd[j*64+lane] = src[j*64+lane];
    __syncthreads();
    #pragma unroll 1
    for (int tt=0; tt<8; tt++){
      long r = r0 + tt;
      const float* row = sxd + tt*40;
      float dtp = bias;
      #pragma unroll
      for (int j=0;j<8;j++) dtp = fmaf(row[j], wdt[j], dtp);
      // softplus (stable)
      float dt = fmaxf(dtp, 0.f) + log1pf(__expf(-fabsf(dtp)));
      float uv = u[r*256 + d];
      float du = dt * uv;
      float yv = 0.f;
      #pragma unroll
      for (int s=0;s<16;s++){
        float dA = __expf(dt*a[s]);
        hst[s] = fmaf(dA, hst[s], du * row[8+s]);
        yv = fmaf(hst[s], row[24+s], yv);
      }
      float zv = xz[r*512 + 256 + d];
      y[r*256 + d] = (yv + uv*Dpd) * (zv * sigmoidf_(zv));
    }
    __syncthreads();
  }
}

// ---------------- GEMM3: h[BL,128] += y[BL,256] @ out_w[128,256]^T ----------------
// block: 256 thr = 2 groups x 128 cols, 8 rows/group, 16 rows/block
__global__ __launch_bounds__(256) void k_gemm_out(const float* __restrict__ y,
    const float* __restrict__ W, float* __restrict__ h){
  __shared__ float4 As[16][64];    // 16 KB
  int tid = threadIdx.x;
  long r0 = (long)blockIdx.x * 16;
  const float4* src = (const float4*)(y + r0*256);
  #pragma unroll
  for (int j=0;j<4;j++) ((float4*)As)[tid + j*256] = src[tid + j*256];
  __syncthreads();
  int g = tid >> 7, c = tid & 127;
  const float4* w = (const float4*)(W + (long)c*256);
  float acc[8];
  #pragma unroll
  for (int r=0;r<8;r++) acc[r]=0.f;
  for (int k=0;k<64;k++){
    float4 wv = w[k];
    #pragma unroll
    for (int r=0;r<8;r++){
      float4 av = As[g*8+r][k];
      acc[r] = fmaf(av.x,wv.x,fmaf(av.y,wv.y,fmaf(av.z,wv.z,fmaf(av.w,wv.w,acc[r]))));
    }
  }
  #pragma unroll
  for (int r=0;r<8;r++){
    long rr = r0 + g*8 + r;
    h[rr*128 + c] += acc[r];
  }
}

// ---------------- mean pool over t ----------------
__global__ __launch_bounds__(128) void k_pool(const float* __restrict__ n, float* __restrict__ pooled){
  int b = blockIdx.x, c = threadIdx.x;
  const float* base = n + (long)b*1000*128 + c;
  float s = 0.f;
  for (int t=0;t<1000;t++) s += base[(long)t*128];
  pooled[b*128 + c] = s * 1e-3f;
}

// ---------------- head: out[b,c] = pooled[b] . head_w[c] + head_b[c] ----------------
__global__ __launch_bounds__(128) void k_head(const float* __restrict__ pooled,
    const float* __restrict__ hw, const float* __restrict__ hb, float* __restrict__ out){
  __shared__ float sp[128];
  int b = blockIdx.x, c = threadIdx.x;
  sp[c] = pooled[b*128 + c];
  __syncthreads();
  if (c < 71){
    const float* w = hw + c*128;
    float acc = hb[c];
    #pragma unroll
    for (int k=0;k<128;k++) acc = fmaf(sp[k], w[k], acc);
    out[b*71 + c] = acc;
  }
}

extern "C" void kernel_launch(void* const* d_in, const int* in_sizes, int n_in,
                              void* d_out, int out_size, void* d_ws, size_t ws_size,
                              hipStream_t stream){
  const float* x      = (const float*)d_in[0];
  const float* inp_w  = (const float*)d_in[1];
  const float* inp_b  = (const float*)d_in[2];
  const float* ln_w   = (const float*)d_in[3];
  const float* ln_b   = (const float*)d_in[4];
  const float* in_w   = (const float*)d_in[5];
  const float* conv_w = (const float*)d_in[6];
  const float* conv_b = (const float*)d_in[7];
  const float* xp_w   = (const float*)d_in[8];
  const float* dtp_w  = (const float*)d_in[9];
  const float* dtp_b  = (const float*)d_in[10];
  const float* A_log  = (const float*)d_in[11];
  const float* Dp     = (const float*)d_in[12];
  const float* out_w  = (const float*)d_in[13];
  const float* fn_w   = (const float*)d_in[14];
  const float* fn_b   = (const float*)d_in[15];
  const float* head_w = (const float*)d_in[16];
  const float* head_b = (const float*)d_in[17];

  float* ws  = (float*)d_ws;
  float* h    = ws;               // 4,096,000
  float* xzb  = ws +  4096000;    // 16,384,000
  float* ub   = ws + 20480000;    //  8,192,000
  float* xdb  = ws + 28672000;    //  1,280,000
  float* nyb  = ws + 29952000;    //  8,192,000  (n occupies first half; y reuses whole region)
  float* pooled = ws + 38144000;  //  4,096
  float* nb = nyb;   // LN output (dead after gemm_xz)
  float* yb = nyb;   // scan output (written after n is consumed)

  k_inproj<<<BLROWS*128/256, 256, 0, stream>>>(x, inp_w, inp_b, h);
  for (int i=0;i<6;i++){
    k_ln      <<<BLROWS/4,  256, 0, stream>>>(h, ln_w + i*128, ln_b + i*128, nb);
    k_gemm_xz <<<BLROWS/16, 256, 0, stream>>>(nb, in_w + (long)i*512*128, xzb);
    k_conv    <<<BLROWS,    256, 0, stream>>>(xzb, conv_w + i*1024, conv_b + i*256, ub);
    k_gemm_xdbl<<<BLROWS/32,256, 0, stream>>>(ub, xp_w + (long)i*40*256, xdb);
    k_scan    <<<NBATCH*4,   64, 0, stream>>>(xzb, ub, xdb, dtp_w + i*2048, dtp_b + i*256,
                                              A_log + i*4096, Dp + i*256, yb);
    k_gemm_out<<<BLROWS/16, 256, 0, stream>>>(yb, out_w + (long)i*128*256, h);
  }
  k_ln  <<<BLROWS/4, 256, 0, stream>>>(h, fn_w, fn_b, nb);
  k_pool<<<NBATCH,   128, 0, stream>>>(nb, pooled);
  k_head<<<NBATCH,   128, 0, stream>>>(pooled, head_w, head_b, (float*)d_out);
}

// Round 2
// 2677.972 us; speedup vs baseline: 1.8284x; 1.8284x over previous
//
#include <hip/hip_runtime.h>
#include <math.h>

#define BLROWS 32000   // B*L = 32*1000
#define LSEQ   1000
#define NBATCH 32

__device__ __forceinline__ float sigmoidf_(float x){ return 1.f/(1.f+__expf(-x)); }

// DPP-based partial-row reduction helper: x += perm(x), CTRL is a DPP control code.
template<int CTRL>
__device__ __forceinline__ float dpp_add_(float x){
  int t = __builtin_amdgcn_update_dpp(0, __float_as_int(x), CTRL, 0xf, 0xf, true);
  return x + __int_as_float(t);
}
// Full sum across each aligned 16-lane group (quad xor1, xor2, then row_ror 4, 8).
__device__ __forceinline__ float red16_(float x){
  x = dpp_add_<0xB1>(x);    // quad_perm [1,0,3,2]  (xor 1)
  x = dpp_add_<0x4E>(x);    // quad_perm [2,3,0,1]  (xor 2)
  x = dpp_add_<0x124>(x);   // row_ror:4
  x = dpp_add_<0x128>(x);   // row_ror:8
  return x;
}

// ---------------- input projection: h = x @ inp_w.T + inp_b ----------------
__global__ __launch_bounds__(256) void k_inproj(const float* __restrict__ x,
    const float* __restrict__ w, const float* __restrict__ bias, float* __restrict__ h){
  int idx = blockIdx.x*256 + threadIdx.x;    // r*128 + c
  int r = idx >> 7, c = idx & 127;
  const float* xr = x + (long)r*12;
  const float* wr = w + c*12;
  float acc = bias[c];
  #pragma unroll
  for (int k=0;k<12;k++) acc = fmaf(xr[k], wr[k], acc);
  h[idx] = acc;
}

// ---------------- layernorm: one wave per row of 128 ----------------
__global__ __launch_bounds__(256) void k_ln(const float* __restrict__ h,
    const float* __restrict__ w, const float* __restrict__ b, float* __restrict__ out){
  int wv = threadIdx.x >> 6, lane = threadIdx.x & 63;
  long r = (long)blockIdx.x*4 + wv;
  float2 v = ((const float2*)(h + r*128))[lane];
  float s = v.x + v.y;
  #pragma unroll
  for (int m=32;m>=1;m>>=1) s += __shfl_xor(s, m);
  float mu = s * (1.f/128.f);
  float dx = v.x - mu, dy = v.y - mu;
  float q = dx*dx + dy*dy;
  #pragma unroll
  for (int m=32;m>=1;m>>=1) q += __shfl_xor(q, m);
  float rstd = rsqrtf(q*(1.f/128.f) + 1e-5f);
  float2 wvv = ((const float2*)w)[lane];
  float2 bvv = ((const float2*)b)[lane];
  float2 o; o.x = dx*rstd*wvv.x + bvv.x; o.y = dy*rstd*wvv.y + bvv.y;
  ((float2*)(out + r*128))[lane] = o;
}

// ---------------- GEMM1: xz[BL,512] = n[BL,128] @ W[512,128]^T ----------------
__global__ __launch_bounds__(256) void k_gemm_xz(const float* __restrict__ n,
    const float* __restrict__ W, float* __restrict__ xz){
  __shared__ float4 As[16][32];     // 16 rows x 128 floats
  int tid = threadIdx.x;
  long r0 = (long)blockIdx.x * 16;
  const float4* src = (const float4*)(n + r0*128);
  ((float4*)As)[tid]     = src[tid];
  ((float4*)As)[tid+256] = src[tid+256];
  __syncthreads();
  const float4* w0 = (const float4*)(W + (long)tid*128);
  const float4* w1 = (const float4*)(W + (long)(tid+256)*128);
  float acc0[16], acc1[16];
  #pragma unroll
  for (int r=0;r<16;r++){ acc0[r]=0.f; acc1[r]=0.f; }
  for (int k=0;k<32;k++){
    float4 a = w0[k], c = w1[k];
    #pragma unroll
    for (int r=0;r<16;r++){
      float4 av = As[r][k];
      acc0[r] = fmaf(av.x,a.x,fmaf(av.y,a.y,fmaf(av.z,a.z,fmaf(av.w,a.w,acc0[r]))));
      acc1[r] = fmaf(av.x,c.x,fmaf(av.y,c.y,fmaf(av.z,c.z,fmaf(av.w,c.w,acc1[r]))));
    }
  }
  float* orow = xz + r0*512;
  #pragma unroll
  for (int r=0;r<16;r++){
    orow[(long)r*512 + tid]       = acc0[r];
    orow[(long)r*512 + tid + 256] = acc1[r];
  }
}

// ---------------- causal depthwise conv (K=4) + SiLU ----------------
__global__ __launch_bounds__(256) void k_conv(const float* __restrict__ xz,
    const float* __restrict__ cw, const float* __restrict__ cb, float* __restrict__ u){
  long r = blockIdx.x; int d = threadIdx.x;
  int t = (int)(r % 1000);
  float w0=cw[d*4+0], w1=cw[d*4+1], w2=cw[d*4+2], w3=cw[d*4+3];
  const float* base = xz + r*512 + d;
  float acc = cb[d] + base[0]*w3;
  if (t>=1) acc = fmaf(base[-512],  w2, acc);
  if (t>=2) acc = fmaf(base[-1024], w1, acc);
  if (t>=3) acc = fmaf(base[-1536], w0, acc);
  u[r*256 + d] = acc * sigmoidf_(acc);
}

// ---------------- GEMM2: x_dbl[BL,40] = u[BL,256] @ xp_w[40,256]^T ----------------
__global__ __launch_bounds__(256) void k_gemm_xdbl(const float* __restrict__ u,
    const float* __restrict__ W, float* __restrict__ xd){
  __shared__ float4 As[32][64];    // 32 KB
  int tid = threadIdx.x;
  long r0 = (long)blockIdx.x * 32;
  const float4* src = (const float4*)(u + r0*256);
  #pragma unroll
  for (int j=0;j<8;j++) ((float4*)As)[tid + j*256] = src[tid + j*256];
  __syncthreads();
  int g = tid >> 6, c = tid & 63;
  int ce = c < 40 ? c : 39;
  const float4* w = (const float4*)(W + (long)ce*256);
  float acc[8];
  #pragma unroll
  for (int r=0;r<8;r++) acc[r]=0.f;
  for (int k=0;k<64;k++){
    float4 wv = w[k];
    #pragma unroll
    for (int r=0;r<8;r++){
      float4 av = As[g*8+r][k];
      acc[r] = fmaf(av.x,wv.x,fmaf(av.y,wv.y,fmaf(av.z,wv.z,fmaf(av.w,wv.w,acc[r]))));
    }
  }
  if (c < 40){
    #pragma unroll
    for (int r=0;r<8;r++) xd[(r0 + g*8 + r)*40 + c] = acc[r];
  }
}

// ---------------- fused dt-proj + softplus + selective scan + gating (v2) ----------------
// One thread per (channel, state). Block 256 = 16 channels x 16 states.
// Grid = 32 b x 16 cgroups = 512 blocks -> 2048 waves (8 waves/CU).
// Chunked over 16 timesteps: staging phase precomputes dt (softplus), u, silu(z), B, C
// into LDS; inner loop is 1 exp + few FMA + DPP 16-lane reduction per step.
__global__ __launch_bounds__(256) void k_scan(const float* __restrict__ xz,
    const float* __restrict__ u, const float* __restrict__ xd,
    const float* __restrict__ dtw, const float* __restrict__ dtb,
    const float* __restrict__ alog, const float* __restrict__ Dp,
    float* __restrict__ y){
  int b  = blockIdx.x >> 4;
  int cg = blockIdx.x & 15;
  int tid = threadIdx.x;
  int d_sub = tid >> 4;          // this thread's channel slot (0..15)
  int s     = tid & 15;          // this thread's state index  (0..15)
  int c0 = cg*16;
  int d  = c0 + d_sub;           // global channel
  // staging-role indices: tq = time slot (0..15), cp = position (0..15)
  int tq = d_sub, cp = s;

  float a   = -__expf(alog[d*16 + s]);
  float Dpd = Dp[d];
  float h   = 0.f;
  float wdt[8];
  #pragma unroll
  for (int j=0;j<8;j++) wdt[j] = dtw[d*8+j];
  float bias = dtb[d];

  __shared__ float  sdt[256];    // [t][channel]
  __shared__ float2 suz[256];    // [t][channel] = {u, silu(z)}
  __shared__ float2 sbc[256];    // [t][state]   = {B, C}
  __shared__ float  sy [256];    // [t][channel]

  long rbase = (long)b*1000;
  for (int tc=0; tc<63; tc++){
    int t0 = tc*16;
    // ---- stage (no barrier needed before: writes race only with prior chunk's
    //      reads, which completed before the second barrier below) ----
    long r_u = rbase + t0 + tq; if (r_u > 31999) r_u = 31999;   // clamp: phantom tail rows
    long r_d = rbase + t0 + cp; if (r_d > 31999) r_d = 31999;
    float uv = u[r_u*256 + c0 + cp];
    float zv = xz[r_u*512 + 256 + c0 + cp];
    suz[tq*16 + cp] = make_float2(uv, zv * sigmoidf_(zv));
    const float* xr = xd + r_u*40;
    sbc[tq*16 + cp] = make_float2(xr[8 + cp], xr[24 + cp]);
    // dt for (t = cp, channel = d): uses this thread's own wdt/bias
    const float* xrd = xd + r_d*40;
    float dtp = bias;
    #pragma unroll
    for (int j=0;j<8;j++) dtp = fmaf(xrd[j], wdt[j], dtp);
    sdt[cp*16 + tq] = fmaxf(dtp, 0.f) + log1pf(__expf(-fabsf(dtp)));
    __syncthreads();
    // ---- inner 16 timesteps ----
    #pragma unroll
    for (int tt=0; tt<16; tt++){
      float dt  = sdt[tt*16 + d_sub];
      float2 uz = suz[tt*16 + d_sub];
      float2 bc = sbc[tt*16 + s];
      float dA = __expf(dt * a);
      h = fmaf(dA, h, dt * uz.x * bc.x);
      float pr = red16_(h * bc.y);
      if (s == 0) sy[tt*16 + d_sub] = fmaf(uz.x, Dpd, pr) * uz.y;
    }
    __syncthreads();
    // ---- coalesced writeout ----
    int t = t0 + tq;
    if (t < 1000) y[(rbase + t)*256 + c0 + cp] = sy[tq*16 + cp];
  }
}

// ---------------- GEMM3: h[BL,128] += y[BL,256] @ out_w[128,256]^T ----------------
__global__ __launch_bounds__(256) void k_gemm_out(const float* __restrict__ y,
    const float* __restrict__ W, float* __restrict__ h){
  __shared__ float4 As[16][64];    // 16 KB
  int tid = threadIdx.x;
  long r0 = (long)blockIdx.x * 16;
  const float4* src = (const float4*)(y + r0*256);
  #pragma unroll
  for (int j=0;j<4;j++) ((float4*)As)[tid + j*256] = src[tid + j*256];
  __syncthreads();
  int g = tid >> 7, c = tid & 127;
  const float4* w = (const float4*)(W + (long)c*256);
  float acc[8];
  #pragma unroll
  for (int r=0;r<8;r++) acc[r]=0.f;
  for (int k=0;k<64;k++){
    float4 wv = w[k];
    #pragma unroll
    for (int r=0;r<8;r++){
      float4 av = As[g*8+r][k];
      acc[r] = fmaf(av.x,wv.x,fmaf(av.y,wv.y,fmaf(av.z,wv.z,fmaf(av.w,wv.w,acc[r]))));
    }
  }
  #pragma unroll
  for (int r=0;r<8;r++){
    long rr = r0 + g*8 + r;
    h[rr*128 + c] += acc[r];
  }
}

// ---------------- mean pool over t ----------------
__global__ __launch_bounds__(128) void k_pool(const float* __restrict__ n, float* __restrict__ pooled){
  int b = blockIdx.x, c = threadIdx.x;
  const float* base = n + (long)b*1000*128 + c;
  float s = 0.f;
  for (int t=0;t<1000;t++) s += base[(long)t*128];
  pooled[b*128 + c] = s * 1e-3f;
}

// ---------------- head ----------------
__global__ __launch_bounds__(128) void k_head(const float* __restrict__ pooled,
    const float* __restrict__ hw, const float* __restrict__ hb, float* __restrict__ out){
  __shared__ float sp[128];
  int b = blockIdx.x, c = threadIdx.x;
  sp[c] = pooled[b*128 + c];
  __syncthreads();
  if (c < 71){
    const float* w = hw + c*128;
    float acc = hb[c];
    #pragma unroll
    for (int k=0;k<128;k++) acc = fmaf(sp[k], w[k], acc);
    out[b*71 + c] = acc;
  }
}

extern "C" void kernel_launch(void* const* d_in, const int* in_sizes, int n_in,
                              void* d_out, int out_size, void* d_ws, size_t ws_size,
                              hipStream_t stream){
  const float* x      = (const float*)d_in[0];
  const float* inp_w  = (const float*)d_in[1];
  const float* inp_b  = (const float*)d_in[2];
  const float* ln_w   = (const float*)d_in[3];
  const float* ln_b   = (const float*)d_in[4];
  const float* in_w   = (const float*)d_in[5];
  const float* conv_w = (const float*)d_in[6];
  const float* conv_b = (const float*)d_in[7];
  const float* xp_w   = (const float*)d_in[8];
  const float* dtp_w  = (const float*)d_in[9];
  const float* dtp_b  = (const float*)d_in[10];
  const float* A_log  = (const float*)d_in[11];
  const float* Dp     = (const float*)d_in[12];
  const float* out_w  = (const float*)d_in[13];
  const float* fn_w   = (const float*)d_in[14];
  const float* fn_b   = (const float*)d_in[15];
  const float* head_w = (const float*)d_in[16];
  const float* head_b = (const float*)d_in[17];

  float* ws  = (float*)d_ws;
  float* h    = ws;               // 4,096,000
  float* xzb  = ws +  4096000;    // 16,384,000
  float* ub   = ws + 20480000;    //  8,192,000
  float* xdb  = ws + 28672000;    //  1,280,000
  float* nyb  = ws + 29952000;    //  8,192,000
  float* pooled = ws + 38144000;  //  4,096
  float* nb = nyb;   // LN output (dead after gemm_xz)
  float* yb = nyb;   // scan output (written after n is consumed)

  k_inproj<<<BLROWS*128/256, 256, 0, stream>>>(x, inp_w, inp_b, h);
  for (int i=0;i<6;i++){
    k_ln      <<<BLROWS/4,  256, 0, stream>>>(h, ln_w + i*128, ln_b + i*128, nb);
    k_gemm_xz <<<BLROWS/16, 256, 0, stream>>>(nb, in_w + (long)i*512*128, xzb);
    k_conv    <<<BLROWS,    256, 0, stream>>>(xzb, conv_w + i*1024, conv_b + i*256, ub);
    k_gemm_xdbl<<<BLROWS/32,256, 0, stream>>>(ub, xp_w + (long)i*40*256, xdb);
    k_scan    <<<NBATCH*16, 256, 0, stream>>>(xzb, ub, xdb, dtp_w + i*2048, dtp_b + i*256,
                                              A_log + i*4096, Dp + i*256, yb);
    k_gemm_out<<<BLROWS/16, 256, 0, stream>>>(yb, out_w + (long)i*128*256, h);
  }
  k_ln  <<<BLROWS/4, 256, 0, stream>>>(h, fn_w, fn_b, nb);
  k_pool<<<NBATCH,   128, 0, stream>>>(nb, pooled);
  k_head<<<NBATCH,   128, 0, stream>>>(pooled, head_w, head_b, (float*)d_out);
}

// Round 3
// 2366.105 us; speedup vs baseline: 2.0694x; 1.1318x over previous
//
#include <hip/hip_runtime.h>
#include <math.h>

#define BLROWS 32000   // B*L = 32*1000
#define LSEQ   1000
#define NBATCH 32
#define NC     25      // time chunks
#define TC     40      // timesteps per chunk (NC*TC = 1000)

__device__ __forceinline__ float sigmoidf_(float x){ return 1.f/(1.f+__expf(-x)); }

// ---------------- input projection: h = x @ inp_w.T + inp_b ----------------
__global__ __launch_bounds__(256) void k_inproj(const float* __restrict__ x,
    const float* __restrict__ w, const float* __restrict__ bias, float* __restrict__ h){
  int idx = blockIdx.x*256 + threadIdx.x;    // r*128 + c
  int r = idx >> 7, c = idx & 127;
  const float* xr = x + (long)r*12;
  const float* wr = w + c*12;
  float acc = bias[c];
  #pragma unroll
  for (int k=0;k<12;k++) acc = fmaf(xr[k], wr[k], acc);
  h[idx] = acc;
}

// ---------------- layernorm: one wave per row of 128 ----------------
__global__ __launch_bounds__(256) void k_ln(const float* __restrict__ h,
    const float* __restrict__ w, const float* __restrict__ b, float* __restrict__ out){
  int wv = threadIdx.x >> 6, lane = threadIdx.x & 63;
  long r = (long)blockIdx.x*4 + wv;
  float2 v = ((const float2*)(h + r*128))[lane];
  float s = v.x + v.y;
  #pragma unroll
  for (int m=32;m>=1;m>>=1) s += __shfl_xor(s, m);
  float mu = s * (1.f/128.f);
  float dx = v.x - mu, dy = v.y - mu;
  float q = dx*dx + dy*dy;
  #pragma unroll
  for (int m=32;m>=1;m>>=1) q += __shfl_xor(q, m);
  float rstd = rsqrtf(q*(1.f/128.f) + 1e-5f);
  float2 wvv = ((const float2*)w)[lane];
  float2 bvv = ((const float2*)b)[lane];
  float2 o; o.x = dx*rstd*wvv.x + bvv.x; o.y = dy*rstd*wvv.y + bvv.y;
  ((float2*)(out + r*128))[lane] = o;
}

// ---------------- GEMM1: xz[BL,512] = n[BL,128] @ W[512,128]^T ----------------
__global__ __launch_bounds__(256) void k_gemm_xz(const float* __restrict__ n,
    const float* __restrict__ W, float* __restrict__ xz){
  __shared__ float4 As[16][32];     // 16 rows x 128 floats
  int tid = threadIdx.x;
  long r0 = (long)blockIdx.x * 16;
  const float4* src = (const float4*)(n + r0*128);
  ((float4*)As)[tid]     = src[tid];
  ((float4*)As)[tid+256] = src[tid+256];
  __syncthreads();
  const float4* w0 = (const float4*)(W + (long)tid*128);
  const float4* w1 = (const float4*)(W + (long)(tid+256)*128);
  float acc0[16], acc1[16];
  #pragma unroll
  for (int r=0;r<16;r++){ acc0[r]=0.f; acc1[r]=0.f; }
  for (int k=0;k<32;k++){
    float4 a = w0[k], c = w1[k];
    #pragma unroll
    for (int r=0;r<16;r++){
      float4 av = As[r][k];
      acc0[r] = fmaf(av.x,a.x,fmaf(av.y,a.y,fmaf(av.z,a.z,fmaf(av.w,a.w,acc0[r]))));
      acc1[r] = fmaf(av.x,c.x,fmaf(av.y,c.y,fmaf(av.z,c.z,fmaf(av.w,c.w,acc1[r]))));
    }
  }
  float* orow = xz + r0*512;
  #pragma unroll
  for (int r=0;r<16;r++){
    orow[(long)r*512 + tid]       = acc0[r];
    orow[(long)r*512 + tid + 256] = acc1[r];
  }
}

// ---------------- causal depthwise conv (K=4) + SiLU ----------------
__global__ __launch_bounds__(256) void k_conv(const float* __restrict__ xz,
    const float* __restrict__ cw, const float* __restrict__ cb, float* __restrict__ u){
  long r = blockIdx.x; int d = threadIdx.x;
  int t = (int)(r % 1000);
  float w0=cw[d*4+0], w1=cw[d*4+1], w2=cw[d*4+2], w3=cw[d*4+3];
  const float* base = xz + r*512 + d;
  float acc = cb[d] + base[0]*w3;
  if (t>=1) acc = fmaf(base[-512],  w2, acc);
  if (t>=2) acc = fmaf(base[-1024], w1, acc);
  if (t>=3) acc = fmaf(base[-1536], w0, acc);
  u[r*256 + d] = acc * sigmoidf_(acc);
}

// ---------------- GEMM2 + dt-projection ----------------
// x_dbl[BL,40] = u[BL,256] @ xp_w[40,256]^T ; then dt = softplus(x_dbl[:,:8] @ dtp_w.T + dtp_b)
// dt is stored into the DEAD u-half of xz (xz[r,0:256]) for the scan phases.
__global__ __launch_bounds__(256) void k_gemm_xdbl(const float* __restrict__ u,
    const float* __restrict__ W, const float* __restrict__ dtw, const float* __restrict__ dtb,
    float* __restrict__ xd, float* __restrict__ xz){
  __shared__ float4 As[32][64];    // 32 KB: u rows
  __shared__ float sxd8[32][8];    // x_dbl[:, 0:8] for this block's rows
  int tid = threadIdx.x;
  long r0 = (long)blockIdx.x * 32;
  const float4* src = (const float4*)(u + r0*256);
  #pragma unroll
  for (int j=0;j<8;j++) ((float4*)As)[tid + j*256] = src[tid + j*256];
  __syncthreads();
  int g = tid >> 6, c = tid & 63;
  int ce = c < 40 ? c : 39;
  const float4* w = (const float4*)(W + (long)ce*256);
  float acc[8];
  #pragma unroll
  for (int r=0;r<8;r++) acc[r]=0.f;
  for (int k=0;k<64;k++){
    float4 wv = w[k];
    #pragma unroll
    for (int r=0;r<8;r++){
      float4 av = As[g*8+r][k];
      acc[r] = fmaf(av.x,wv.x,fmaf(av.y,wv.y,fmaf(av.z,wv.z,fmaf(av.w,wv.w,acc[r]))));
    }
  }
  if (c < 40){
    #pragma unroll
    for (int r=0;r<8;r++) xd[(r0 + g*8 + r)*40 + c] = acc[r];
  }
  if (c < 8){
    #pragma unroll
    for (int r=0;r<8;r++) sxd8[g*8 + r][c] = acc[r];
  }
  __syncthreads();
  // dt projection: thread = channel d (0..255), 32 rows
  float4 w0 = ((const float4*)(dtw + tid*8))[0];
  float4 w1 = ((const float4*)(dtw + tid*8))[1];
  float bias = dtb[tid];
  #pragma unroll 4
  for (int r=0;r<32;r++){
    const float* x8 = sxd8[r];     // broadcast reads
    float dtp = bias;
    dtp = fmaf(x8[0],w0.x,dtp); dtp = fmaf(x8[1],w0.y,dtp);
    dtp = fmaf(x8[2],w0.z,dtp); dtp = fmaf(x8[3],w0.w,dtp);
    dtp = fmaf(x8[4],w1.x,dtp); dtp = fmaf(x8[5],w1.y,dtp);
    dtp = fmaf(x8[6],w1.z,dtp); dtp = fmaf(x8[7],w1.w,dtp);
    float dt = fmaxf(dtp, 0.f) + log1pf(__expf(-fabsf(dtp)));
    xz[(r0 + r)*512 + tid] = dt;
  }
}

// ---------------- scan phase 1: per-chunk local scan -> (P, H) summaries ----------------
// thread = channel d; 16 states in registers. Block = 1 wave (64 channels).
// grid = 32 b x 4 dgroups x NC chunks.
__global__ __launch_bounds__(64) void k_scan1(const float* __restrict__ xz,
    const float* __restrict__ u, const float* __restrict__ xd,
    const float* __restrict__ alog, float2* __restrict__ sum){
  int bi = blockIdx.x;
  int c  = bi % NC;
  int dg = (bi / NC) & 3;
  int b  = bi / (NC*4);
  int lane = threadIdx.x;
  int d = dg*64 + lane;
  float a[16];
  #pragma unroll
  for (int j=0;j<4;j++){
    float4 v = ((const float4*)(alog + d*16))[j];
    a[4*j+0] = -__expf(v.x); a[4*j+1] = -__expf(v.y);
    a[4*j+2] = -__expf(v.z); a[4*j+3] = -__expf(v.w);
  }
  __shared__ float sB[TC][16];
  long r0 = (long)b*1000 + c*TC;
  for (int k=lane; k<TC*16; k+=64){
    int j = k>>4, m = k&15;
    sB[j][m] = xd[(r0+j)*40 + 8 + m];
  }
  __syncthreads();
  float P[16], h[16];
  #pragma unroll
  for (int s=0;s<16;s++){ P[s]=1.f; h[s]=0.f; }
  for (int t=0;t<TC;t++){
    long r = r0 + t;
    float dt = xz[r*512 + d];
    float uv = u[r*256 + d];
    float du = dt*uv;
    float4 B0 = ((const float4*)sB[t])[0];
    float4 B1 = ((const float4*)sB[t])[1];
    float4 B2 = ((const float4*)sB[t])[2];
    float4 B3 = ((const float4*)sB[t])[3];
    float Bv[16] = {B0.x,B0.y,B0.z,B0.w, B1.x,B1.y,B1.z,B1.w,
                    B2.x,B2.y,B2.z,B2.w, B3.x,B3.y,B3.z,B3.w};
    #pragma unroll
    for (int s=0;s<16;s++){
      float dA = __expf(dt*a[s]);
      P[s] *= dA;
      h[s] = fmaf(dA, h[s], du*Bv[s]);
    }
  }
  long base = ((long)(c*32 + b)*256 + d)*16;
  float4* o = (float4*)(sum + base);
  #pragma unroll
  for (int j=0;j<8;j++){
    float4 f; f.x = P[2*j]; f.y = h[2*j]; f.z = P[2*j+1]; f.w = h[2*j+1];
    o[j] = f;
  }
}

// ---------------- scan phase 2: compose chunk summaries; write h0 into P-slot ----------------
__global__ __launch_bounds__(256) void k_scan2(float2* __restrict__ sum){
  int g = blockIdx.x*256 + threadIdx.x;   // 131072 = 32*256*16 chains
  long stride = 32L*256*16;               // per-chunk element stride
  long base = g;                          // layout [c][b][d][s] with g = ((b*256+d)*16+s)
  float S = 0.f;
  for (int c=0;c<NC;c++){
    long idx = base + (long)c*stride;
    float2 ph = sum[idx];
    sum[idx].x = S;                       // chunk c's true initial state
    S = fmaf(ph.x, S, ph.y);
  }
}

// ---------------- scan phase 3: re-run chunk from true h0, emit gated y ----------------
// y overwrites the dt slot (xz[r,0:256]) after last use.
__global__ __launch_bounds__(64) void k_scan3(float* __restrict__ xz,
    const float* __restrict__ u, const float* __restrict__ xd,
    const float* __restrict__ alog, const float* __restrict__ Dp,
    const float2* __restrict__ sum){
  int bi = blockIdx.x;
  int c  = bi % NC;
  int dg = (bi / NC) & 3;
  int b  = bi / (NC*4);
  int lane = threadIdx.x;
  int d = dg*64 + lane;
  float a[16];
  #pragma unroll
  for (int j=0;j<4;j++){
    float4 v = ((const float4*)(alog + d*16))[j];
    a[4*j+0] = -__expf(v.x); a[4*j+1] = -__expf(v.y);
    a[4*j+2] = -__expf(v.z); a[4*j+3] = -__expf(v.w);
  }
  float Dpd = Dp[d];
  __shared__ float sBC[TC][32];
  long r0 = (long)b*1000 + c*TC;
  for (int k=lane; k<TC*32; k+=64){
    int j = k>>5, m = k&31;
    sBC[j][m] = xd[(r0+j)*40 + 8 + m];
  }
  float h[16];
  long base = ((long)(c*32 + b)*256 + d)*16;
  const float4* hp = (const float4*)(sum + base);
  #pragma unroll
  for (int j=0;j<8;j++){
    float4 f = hp[j];           // {h0(2j), H, h0(2j+1), H}
    h[2*j] = f.x; h[2*j+1] = f.z;
  }
  __syncthreads();
  for (int t=0;t<TC;t++){
    long r = r0 + t;
    float dt = xz[r*512 + d];
    float uv = u[r*256 + d];
    float zv = xz[r*512 + 256 + d];
    float du = dt*uv;
    float4 B0 = ((const float4*)sBC[t])[0];
    float4 B1 = ((const float4*)sBC[t])[1];
    float4 B2 = ((const float4*)sBC[t])[2];
    float4 B3 = ((const float4*)sBC[t])[3];
    float4 C0 = ((const float4*)sBC[t])[4];
    float4 C1 = ((const float4*)sBC[t])[5];
    float4 C2 = ((const float4*)sBC[t])[6];
    float4 C3 = ((const float4*)sBC[t])[7];
    float Bv[16] = {B0.x,B0.y,B0.z,B0.w, B1.x,B1.y,B1.z,B1.w,
                    B2.x,B2.y,B2.z,B2.w, B3.x,B3.y,B3.z,B3.w};
    float Cv[16] = {C0.x,C0.y,C0.z,C0.w, C1.x,C1.y,C1.z,C1.w,
                    C2.x,C2.y,C2.z,C2.w, C3.x,C3.y,C3.z,C3.w};
    float acc = 0.f;
    #pragma unroll
    for (int s=0;s<16;s++){
      float dA = __expf(dt*a[s]);
      h[s] = fmaf(dA, h[s], du*Bv[s]);
      acc = fmaf(h[s], Cv[s], acc);
    }
    float sz = zv * sigmoidf_(zv);
    xz[r*512 + d] = fmaf(uv, Dpd, acc) * sz;   // y into dead dt slot
  }
}

// ---------------- GEMM3: h[BL,128] += y @ out_w[128,256]^T  (y lives in xz[:,0:256]) ----------------
__global__ __launch_bounds__(256) void k_gemm_out(const float* __restrict__ xz,
    const float* __restrict__ W, float* __restrict__ h){
  __shared__ float4 As[16][64];    // 16 KB
  int tid = threadIdx.x;
  long r0 = (long)blockIdx.x * 16;
  #pragma unroll
  for (int j=0;j<4;j++){
    int l = tid + j*256;
    int row = l>>6, col = l&63;
    As[row][col] = ((const float4*)(xz + (r0+row)*512))[col];
  }
  __syncthreads();
  int g = tid >> 7, c = tid & 127;
  const float4* w = (const float4*)(W + (long)c*256);
  float acc[8];
  #pragma unroll
  for (int r=0;r<8;r++) acc[r]=0.f;
  for (int k=0;k<64;k++){
    float4 wv = w[k];
    #pragma unroll
    for (int r=0;r<8;r++){
      float4 av = As[g*8+r][k];
      acc[r] = fmaf(av.x,wv.x,fmaf(av.y,wv.y,fmaf(av.z,wv.z,fmaf(av.w,wv.w,acc[r]))));
    }
  }
  #pragma unroll
  for (int r=0;r<8;r++){
    long rr = r0 + g*8 + r;
    h[rr*128 + c] += acc[r];
  }
}

// ---------------- mean pool over t ----------------
__global__ __launch_bounds__(128) void k_pool(const float* __restrict__ n, float* __restrict__ pooled){
  int b = blockIdx.x, c = threadIdx.x;
  const float* base = n + (long)b*1000*128 + c;
  float s = 0.f;
  for (int t=0;t<1000;t++) s += base[(long)t*128];
  pooled[b*128 + c] = s * 1e-3f;
}

// ---------------- head ----------------
__global__ __launch_bounds__(128) void k_head(const float* __restrict__ pooled,
    const float* __restrict__ hw, const float* __restrict__ hb, float* __restrict__ out){
  __shared__ float sp[128];
  int b = blockIdx.x, c = threadIdx.x;
  sp[c] = pooled[b*128 + c];
  __syncthreads();
  if (c < 71){
    const float* w = hw + c*128;
    float acc = hb[c];
    #pragma unroll
    for (int k=0;k<128;k++) acc = fmaf(sp[k], w[k], acc);
    out[b*71 + c] = acc;
  }
}

extern "C" void kernel_launch(void* const* d_in, const int* in_sizes, int n_in,
                              void* d_out, int out_size, void* d_ws, size_t ws_size,
                              hipStream_t stream){
  const float* x      = (const float*)d_in[0];
  const float* inp_w  = (const float*)d_in[1];
  const float* inp_b  = (const float*)d_in[2];
  const float* ln_w   = (const float*)d_in[3];
  const float* ln_b   = (const float*)d_in[4];
  const float* in_w   = (const float*)d_in[5];
  const float* conv_w = (const float*)d_in[6];
  const float* conv_b = (const float*)d_in[7];
  const float* xp_w   = (const float*)d_in[8];
  const float* dtp_w  = (const float*)d_in[9];
  const float* dtp_b  = (const float*)d_in[10];
  const float* A_log  = (const float*)d_in[11];
  const float* Dp     = (const float*)d_in[12];
  const float* out_w  = (const float*)d_in[13];
  const float* fn_w   = (const float*)d_in[14];
  const float* fn_b   = (const float*)d_in[15];
  const float* head_w = (const float*)d_in[16];
  const float* head_b = (const float*)d_in[17];

  float* ws  = (float*)d_ws;
  float*  h      = ws;               //  4,096,000
  float*  xzb    = ws +  4096000;    // 16,384,000 (dt/y in u-half during scan)
  float*  ub     = ws + 20480000;    //  8,192,000
  float*  xdb    = ws + 28672000;    //  1,280,000
  float*  R      = ws + 29952000;    //  6,553,600 (n before scan; summaries during scan)
  float*  pooled = ws + 36505600;    //  4,096
  float*  nb  = R;
  float2* sum = (float2*)R;

  k_inproj<<<BLROWS*128/256, 256, 0, stream>>>(x, inp_w, inp_b, h);
  for (int i=0;i<6;i++){
    k_ln       <<<BLROWS/4,  256, 0, stream>>>(h, ln_w + i*128, ln_b + i*128, nb);
    k_gemm_xz  <<<BLROWS/16, 256, 0, stream>>>(nb, in_w + (long)i*512*128, xzb);
    k_conv     <<<BLROWS,    256, 0, stream>>>(xzb, conv_w + i*1024, conv_b + i*256, ub);
    k_gemm_xdbl<<<BLROWS/32, 256, 0, stream>>>(ub, xp_w + (long)i*40*256,
                                               dtp_w + i*2048, dtp_b + i*256, xdb, xzb);
    k_scan1    <<<NBATCH*4*NC, 64, 0, stream>>>(xzb, ub, xdb, A_log + i*4096, sum);
    k_scan2    <<<512,        256, 0, stream>>>(sum);
    k_scan3    <<<NBATCH*4*NC, 64, 0, stream>>>(xzb, ub, xdb, A_log + i*4096, Dp + i*256, sum);
    k_gemm_out <<<BLROWS/16, 256, 0, stream>>>(xzb, out_w + (long)i*128*256, h);
  }
  k_ln  <<<BLROWS/4, 256, 0, stream>>>(h, fn_w, fn_b, nb);
  k_pool<<<NBATCH,   128, 0, stream>>>(nb, pooled);
  k_head<<<NBATCH,   128, 0, stream>>>(pooled, head_w, head_b, (float*)d_out);
}

// Round 4
// 1796.165 us; speedup vs baseline: 2.7260x; 1.3173x over previous
//
#include <hip/hip_runtime.h>
#include <math.h>

#define BLROWS 32000   // B*L = 32*1000
#define LSEQ   1000
#define NBATCH 32
#define NC     25      // time chunks
#define TC     40      // timesteps per chunk (NC*TC = 1000)

typedef __attribute__((ext_vector_type(8))) short bf16x8;
typedef __attribute__((ext_vector_type(4))) float f32x4;
typedef unsigned int u32;

__device__ __forceinline__ float sigmoidf_(float x){ return 1.f/(1.f+__expf(-x)); }

// pack float -> (bf16 hi | bf16 lo << 16), both RNE. hi+lo ~= x to ~16 mantissa bits.
__device__ __forceinline__ u32 pack_hilo(float x){
  u32 u = __float_as_uint(x);
  u32 hi = (u + 0x7FFFu + ((u>>16)&1u)) >> 16;
  float rh = __uint_as_float(hi<<16);
  float lf = x - rh;
  u32 ul = __float_as_uint(lf);
  u32 lo = (ul + 0x7FFFu + ((ul>>16)&1u)) >> 16;
  return hi | (lo<<16);
}

// Extract hi-frag and lo-frag (8 bf16 each) from 8 packed dwords.
__device__ __forceinline__ void frags_from(uint4 q0, uint4 q1, bf16x8& hi, bf16x8& lo){
  union { u32 u[4]; bf16x8 v; } H, L;
  H.u[0] = __builtin_amdgcn_perm(q0.y, q0.x, 0x05040100u);
  H.u[1] = __builtin_amdgcn_perm(q0.w, q0.z, 0x05040100u);
  H.u[2] = __builtin_amdgcn_perm(q1.y, q1.x, 0x05040100u);
  H.u[3] = __builtin_amdgcn_perm(q1.w, q1.z, 0x05040100u);
  L.u[0] = __builtin_amdgcn_perm(q0.y, q0.x, 0x07060302u);
  L.u[1] = __builtin_amdgcn_perm(q0.w, q0.z, 0x07060302u);
  L.u[2] = __builtin_amdgcn_perm(q1.y, q1.x, 0x07060302u);
  L.u[3] = __builtin_amdgcn_perm(q1.w, q1.z, 0x07060302u);
  hi = H.v; lo = L.v;
}

#define MFMA16(a,b,c) __builtin_amdgcn_mfma_f32_16x16x32_bf16((a),(b),(c),0,0,0)

// ---------------- weight cast: fp32 -> packed hi/lo bf16 ----------------
__global__ __launch_bounds__(256) void k_castw(const float* __restrict__ a, u32* __restrict__ o, int n){
  int i = blockIdx.x*256 + threadIdx.x;
  if (i < n) o[i] = pack_hilo(a[i]);
}

// ---------------- input projection: h = x @ inp_w.T + inp_b ----------------
__global__ __launch_bounds__(256) void k_inproj(const float* __restrict__ x,
    const float* __restrict__ w, const float* __restrict__ bias, float* __restrict__ h){
  int idx = blockIdx.x*256 + threadIdx.x;    // r*128 + c
  int r = idx >> 7, c = idx & 127;
  const float* xr = x + (long)r*12;
  const float* wr = w + c*12;
  float acc = bias[c];
  #pragma unroll
  for (int k=0;k<12;k++) acc = fmaf(xr[k], wr[k], acc);
  h[idx] = acc;
}

// ---------------- layernorm (fp32 out, used for final LN) ----------------
__global__ __launch_bounds__(256) void k_ln(const float* __restrict__ h,
    const float* __restrict__ w, const float* __restrict__ b, float* __restrict__ out){
  int wv = threadIdx.x >> 6, lane = threadIdx.x & 63;
  long r = (long)blockIdx.x*4 + wv;
  float2 v = ((const float2*)(h + r*128))[lane];
  float s = v.x + v.y;
  #pragma unroll
  for (int m=32;m>=1;m>>=1) s += __shfl_xor(s, m);
  float mu = s * (1.f/128.f);
  float dx = v.x - mu, dy = v.y - mu;
  float q = dx*dx + dy*dy;
  #pragma unroll
  for (int m=32;m>=1;m>>=1) q += __shfl_xor(q, m);
  float rstd = rsqrtf(q*(1.f/128.f) + 1e-5f);
  float2 wvv = ((const float2*)w)[lane];
  float2 bvv = ((const float2*)b)[lane];
  float2 o; o.x = dx*rstd*wvv.x + bvv.x; o.y = dy*rstd*wvv.y + bvv.y;
  ((float2*)(out + r*128))[lane] = o;
}

// ---------------- layernorm with packed hi/lo bf16 output ----------------
__global__ __launch_bounds__(256) void k_ln_bf(const float* __restrict__ h,
    const float* __restrict__ w, const float* __restrict__ b, u32* __restrict__ out){
  int wv = threadIdx.x >> 6, lane = threadIdx.x & 63;
  long r = (long)blockIdx.x*4 + wv;
  float2 v = ((const float2*)(h + r*128))[lane];
  float s = v.x + v.y;
  #pragma unroll
  for (int m=32;m>=1;m>>=1) s += __shfl_xor(s, m);
  float mu = s * (1.f/128.f);
  float dx = v.x - mu, dy = v.y - mu;
  float q = dx*dx + dy*dy;
  #pragma unroll
  for (int m=32;m>=1;m>>=1) q += __shfl_xor(q, m);
  float rstd = rsqrtf(q*(1.f/128.f) + 1e-5f);
  float2 wvv = ((const float2*)w)[lane];
  float2 bvv = ((const float2*)b)[lane];
  uint2 o; o.x = pack_hilo(dx*rstd*wvv.x + bvv.x); o.y = pack_hilo(dy*rstd*wvv.y + bvv.y);
  ((uint2*)(out + r*128))[lane] = o;
}

// ---------------- MFMA GEMM1: xz[BL,512] = n[BL,128] @ in_w[512,128]^T ----------------
// one wave per 64(m) x 32(n) tile; 3-term hi/lo mfma; no LDS (operands via L1/L2).
__global__ __launch_bounds__(64) void k_mm1(const u32* __restrict__ A,
    const u32* __restrict__ W, float* __restrict__ xz){
  int r0 = blockIdx.x*64, n0 = blockIdx.y*32;
  int lane = threadIdx.x;
  int mrow = lane & 15, quad = lane >> 4;
  f32x4 acc[4][2];
  #pragma unroll
  for (int mi=0;mi<4;mi++)
    #pragma unroll
    for (int ni=0;ni<2;ni++) acc[mi][ni] = (f32x4)(0.f);
  #pragma unroll
  for (int ki=0; ki<4; ki++){
    int kb = ki*32 + quad*8;
    bf16x8 ah[4], al[4], wh[2], wl[2];
    #pragma unroll
    for (int mi=0;mi<4;mi++){
      const u32* p = A + (long)(r0+mi*16+mrow)*128 + kb;
      frags_from(*(const uint4*)p, *(const uint4*)(p+4), ah[mi], al[mi]);
    }
    #pragma unroll
    for (int ni=0;ni<2;ni++){
      const u32* p = W + (long)(n0+ni*16+mrow)*128 + kb;
      frags_from(*(const uint4*)p, *(const uint4*)(p+4), wh[ni], wl[ni]);
    }
    #pragma unroll
    for (int mi=0;mi<4;mi++)
      #pragma unroll
      for (int ni=0;ni<2;ni++){
        acc[mi][ni] = MFMA16(ah[mi], wh[ni], acc[mi][ni]);
        acc[mi][ni] = MFMA16(ah[mi], wl[ni], acc[mi][ni]);
        acc[mi][ni] = MFMA16(al[mi], wh[ni], acc[mi][ni]);
      }
  }
  #pragma unroll
  for (int mi=0;mi<4;mi++)
    #pragma unroll
    for (int ni=0;ni<2;ni++)
      #pragma unroll
      for (int rg=0;rg<4;rg++)
        xz[(long)(r0+mi*16+quad*4+rg)*512 + n0+ni*16+mrow] = acc[mi][ni][rg];
}

// ---------------- MFMA GEMM3: h[BL,128] += y[BL,256] @ out_w[128,256]^T ----------------
// y is packed hi/lo in xz[:,0:256] slots (stride 512 u32/row).
__global__ __launch_bounds__(64) void k_mm3(const u32* __restrict__ Y,
    const u32* __restrict__ W, float* __restrict__ h){
  int r0 = blockIdx.x*64, n0 = blockIdx.y*32;
  int lane = threadIdx.x;
  int mrow = lane & 15, quad = lane >> 4;
  f32x4 acc[4][2];
  #pragma unroll
  for (int mi=0;mi<4;mi++)
    #pragma unroll
    for (int ni=0;ni<2;ni++) acc[mi][ni] = (f32x4)(0.f);
  #pragma unroll
  for (int ki=0; ki<8; ki++){
    int kb = ki*32 + quad*8;
    bf16x8 ah[4], al[4], wh[2], wl[2];
    #pragma unroll
    for (int mi=0;mi<4;mi++){
      const u32* p = Y + (long)(r0+mi*16+mrow)*512 + kb;
      frags_from(*(const uint4*)p, *(const uint4*)(p+4), ah[mi], al[mi]);
    }
    #pragma unroll
    for (int ni=0;ni<2;ni++){
      const u32* p = W + (long)(n0+ni*16+mrow)*256 + kb;
      frags_from(*(const uint4*)p, *(const uint4*)(p+4), wh[ni], wl[ni]);
    }
    #pragma unroll
    for (int mi=0;mi<4;mi++)
      #pragma unroll
      for (int ni=0;ni<2;ni++){
        acc[mi][ni] = MFMA16(ah[mi], wh[ni], acc[mi][ni]);
        acc[mi][ni] = MFMA16(ah[mi], wl[ni], acc[mi][ni]);
        acc[mi][ni] = MFMA16(al[mi], wh[ni], acc[mi][ni]);
      }
  }
  #pragma unroll
  for (int mi=0;mi<4;mi++)
    #pragma unroll
    for (int ni=0;ni<2;ni++)
      #pragma unroll
      for (int rg=0;rg<4;rg++){
        long idx = (long)(r0+mi*16+quad*4+rg)*128 + n0+ni*16+mrow;
        h[idx] += acc[mi][ni][rg];
      }
}

// ---------------- causal depthwise conv (K=4) + SiLU ----------------
__global__ __launch_bounds__(256) void k_conv(const float* __restrict__ xz,
    const float* __restrict__ cw, const float* __restrict__ cb, float* __restrict__ u){
  long r = blockIdx.x; int d = threadIdx.x;
  int t = (int)(r % 1000);
  float w0=cw[d*4+0], w1=cw[d*4+1], w2=cw[d*4+2], w3=cw[d*4+3];
  const float* base = xz + r*512 + d;
  float acc = cb[d] + base[0]*w3;
  if (t>=1) acc = fmaf(base[-512],  w2, acc);
  if (t>=2) acc = fmaf(base[-1024], w1, acc);
  if (t>=3) acc = fmaf(base[-1536], w0, acc);
  u[r*256 + d] = acc * sigmoidf_(acc);
}

// ---------------- GEMM2 + dt-projection (fp32) ----------------
__global__ __launch_bounds__(256) void k_gemm_xdbl(const float* __restrict__ u,
    const float* __restrict__ W, const float* __restrict__ dtw, const float* __restrict__ dtb,
    float* __restrict__ xd, float* __restrict__ xz){
  __shared__ float4 As[32][64];
  __shared__ float sxd8[32][8];
  int tid = threadIdx.x;
  long r0 = (long)blockIdx.x * 32;
  const float4* src = (const float4*)(u + r0*256);
  #pragma unroll
  for (int j=0;j<8;j++) ((float4*)As)[tid + j*256] = src[tid + j*256];
  __syncthreads();
  int g = tid >> 6, c = tid & 63;
  int ce = c < 40 ? c : 39;
  const float4* w = (const float4*)(W + (long)ce*256);
  float acc[8];
  #pragma unroll
  for (int r=0;r<8;r++) acc[r]=0.f;
  for (int k=0;k<64;k++){
    float4 wv = w[k];
    #pragma unroll
    for (int r=0;r<8;r++){
      float4 av = As[g*8+r][k];
      acc[r] = fmaf(av.x,wv.x,fmaf(av.y,wv.y,fmaf(av.z,wv.z,fmaf(av.w,wv.w,acc[r]))));
    }
  }
  if (c < 40){
    #pragma unroll
    for (int r=0;r<8;r++) xd[(r0 + g*8 + r)*40 + c] = acc[r];
  }
  if (c < 8){
    #pragma unroll
    for (int r=0;r<8;r++) sxd8[g*8 + r][c] = acc[r];
  }
  __syncthreads();
  float4 w0 = ((const float4*)(dtw + tid*8))[0];
  float4 w1 = ((const float4*)(dtw + tid*8))[1];
  float bias = dtb[tid];
  #pragma unroll 4
  for (int r=0;r<32;r++){
    const float* x8 = sxd8[r];
    float dtp = bias;
    dtp = fmaf(x8[0],w0.x,dtp); dtp = fmaf(x8[1],w0.y,dtp);
    dtp = fmaf(x8[2],w0.z,dtp); dtp = fmaf(x8[3],w0.w,dtp);
    dtp = fmaf(x8[4],w1.x,dtp); dtp = fmaf(x8[5],w1.y,dtp);
    dtp = fmaf(x8[6],w1.z,dtp); dtp = fmaf(x8[7],w1.w,dtp);
    float dt = fmaxf(dtp, 0.f) + log1pf(__expf(-fabsf(dtp)));
    xz[(r0 + r)*512 + tid] = dt;
  }
}

// ---------------- scan phase 1: per-chunk local scan -> (P, H) summaries ----------------
__global__ __launch_bounds__(64) void k_scan1(const float* __restrict__ xz,
    const float* __restrict__ u, const float* __restrict__ xd,
    const float* __restrict__ alog, float2* __restrict__ sum){
  int bi = blockIdx.x;
  int c  = bi % NC;
  int dg = (bi / NC) & 3;
  int b  = bi / (NC*4);
  int lane = threadIdx.x;
  int d = dg*64 + lane;
  float a[16];
  #pragma unroll
  for (int j=0;j<4;j++){
    float4 v = ((const float4*)(alog + d*16))[j];
    a[4*j+0] = -__expf(v.x); a[4*j+1] = -__expf(v.y);
    a[4*j+2] = -__expf(v.z); a[4*j+3] = -__expf(v.w);
  }
  __shared__ float sB[TC][16];
  long r0 = (long)b*1000 + c*TC;
  for (int k=lane; k<TC*16; k+=64){
    int j = k>>4, m = k&15;
    sB[j][m] = xd[(r0+j)*40 + 8 + m];
  }
  __syncthreads();
  float P[16], h[16];
  #pragma unroll
  for (int s=0;s<16;s++){ P[s]=1.f; h[s]=0.f; }
  for (int t=0;t<TC;t++){
    long r = r0 + t;
    float dt = xz[r*512 + d];
    float uv = u[r*256 + d];
    float du = dt*uv;
    float4 B0 = ((const float4*)sB[t])[0];
    float4 B1 = ((const float4*)sB[t])[1];
    float4 B2 = ((const float4*)sB[t])[2];
    float4 B3 = ((const float4*)sB[t])[3];
    float Bv[16] = {B0.x,B0.y,B0.z,B0.w, B1.x,B1.y,B1.z,B1.w,
                    B2.x,B2.y,B2.z,B2.w, B3.x,B3.y,B3.z,B3.w};
    #pragma unroll
    for (int s=0;s<16;s++){
      float dA = __expf(dt*a[s]);
      P[s] *= dA;
      h[s] = fmaf(dA, h[s], du*Bv[s]);
    }
  }
  long base = ((long)(c*32 + b)*256 + d)*16;
  float4* o = (float4*)(sum + base);
  #pragma unroll
  for (int j=0;j<8;j++){
    float4 f; f.x = P[2*j]; f.y = h[2*j]; f.z = P[2*j+1]; f.w = h[2*j+1];
    o[j] = f;
  }
}

// ---------------- scan phase 2: compose chunk summaries; write h0 into P-slot ----------------
__global__ __launch_bounds__(256) void k_scan2(float2* __restrict__ sum){
  int g = blockIdx.x*256 + threadIdx.x;
  long stride = 32L*256*16;
  long base = g;
  float S = 0.f;
  for (int c=0;c<NC;c++){
    long idx = base + (long)c*stride;
    float2 ph = sum[idx];
    sum[idx].x = S;
    S = fmaf(ph.x, S, ph.y);
  }
}

// ---------------- scan phase 3: re-run chunk from true h0, emit gated y (packed bf16 hi/lo) ----------------
__global__ __launch_bounds__(64) void k_scan3(float* __restrict__ xz,
    const float* __restrict__ u, const float* __restrict__ xd,
    const float* __restrict__ alog, const float* __restrict__ Dp,
    const float2* __restrict__ sum){
  int bi = blockIdx.x;
  int c  = bi % NC;
  int dg = (bi / NC) & 3;
  int b  = bi / (NC*4);
  int lane = threadIdx.x;
  int d = dg*64 + lane;
  float a[16];
  #pragma unroll
  for (int j=0;j<4;j++){
    float4 v = ((const float4*)(alog + d*16))[j];
    a[4*j+0] = -__expf(v.x); a[4*j+1] = -__expf(v.y);
    a[4*j+2] = -__expf(v.z); a[4*j+3] = -__expf(v.w);
  }
  float Dpd = Dp[d];
  __shared__ float sBC[TC][32];
  long r0 = (long)b*1000 + c*TC;
  for (int k=lane; k<TC*32; k+=64){
    int j = k>>5, m = k&31;
    sBC[j][m] = xd[(r0+j)*40 + 8 + m];
  }
  float h[16];
  long base = ((long)(c*32 + b)*256 + d)*16;
  const float4* hp = (const float4*)(sum + base);
  #pragma unroll
  for (int j=0;j<8;j++){
    float4 f = hp[j];
    h[2*j] = f.x; h[2*j+1] = f.z;
  }
  __syncthreads();
  u32* yz = (u32*)xz;
  for (int t=0;t<TC;t++){
    long r = r0 + t;
    float dt = xz[r*512 + d];
    float uv = u[r*256 + d];
    float zv = xz[r*512 + 256 + d];
    float du = dt*uv;
    float4 B0 = ((const float4*)sBC[t])[0];
    float4 B1 = ((const float4*)sBC[t])[1];
    float4 B2 = ((const float4*)sBC[t])[2];
    float4 B3 = ((const float4*)sBC[t])[3];
    float4 C0 = ((const float4*)sBC[t])[4];
    float4 C1 = ((const float4*)sBC[t])[5];
    float4 C2 = ((const float4*)sBC[t])[6];
    float4 C3 = ((const float4*)sBC[t])[7];
    float Bv[16] = {B0.x,B0.y,B0.z,B0.w, B1.x,B1.y,B1.z,B1.w,
                    B2.x,B2.y,B2.z,B2.w, B3.x,B3.y,B3.z,B3.w};
    float Cv[16] = {C0.x,C0.y,C0.z,C0.w, C1.x,C1.y,C1.z,C1.w,
                    C2.x,C2.y,C2.z,C2.w, C3.x,C3.y,C3.z,C3.w};
    float acc = 0.f;
    #pragma unroll
    for (int s=0;s<16;s++){
      float dA = __expf(dt*a[s]);
      h[s] = fmaf(dA, h[s], du*Bv[s]);
      acc = fmaf(h[s], Cv[s], acc);
    }
    float sz = zv * sigmoidf_(zv);
    // y packed into this thread's own (dead) dt slot — per-thread exclusive, race-free
    yz[r*512 + d] = pack_hilo(fmaf(uv, Dpd, acc) * sz);
  }
}

// ---------------- mean pool over t ----------------
__global__ __launch_bounds__(128) void k_pool(const float* __restrict__ n, float* __restrict__ pooled){
  int b = blockIdx.x, c = threadIdx.x;
  const float* base = n + (long)b*1000*128 + c;
  float s = 0.f;
  for (int t=0;t<1000;t++) s += base[(long)t*128];
  pooled[b*128 + c] = s * 1e-3f;
}

// ---------------- head ----------------
__global__ __launch_bounds__(128) void k_head(const float* __restrict__ pooled,
    const float* __restrict__ hw, const float* __restrict__ hb, float* __restrict__ out){
  __shared__ float sp[128];
  int b = blockIdx.x, c = threadIdx.x;
  sp[c] = pooled[b*128 + c];
  __syncthreads();
  if (c < 71){
    const float* w = hw + c*128;
    float acc = hb[c];
    #pragma unroll
    for (int k=0;k<128;k++) acc = fmaf(sp[k], w[k], acc);
    out[b*71 + c] = acc;
  }
}

extern "C" void kernel_launch(void* const* d_in, const int* in_sizes, int n_in,
                              void* d_out, int out_size, void* d_ws, size_t ws_size,
                              hipStream_t stream){
  const float* x      = (const float*)d_in[0];
  const float* inp_w  = (const float*)d_in[1];
  const float* inp_b  = (const float*)d_in[2];
  const float* ln_w   = (const float*)d_in[3];
  const float* ln_b   = (const float*)d_in[4];
  const float* in_w   = (const float*)d_in[5];
  const float* conv_w = (const float*)d_in[6];
  const float* conv_b = (const float*)d_in[7];
  const float* xp_w   = (const float*)d_in[8];
  const float* dtp_w  = (const float*)d_in[9];
  const float* dtp_b  = (const float*)d_in[10];
  const float* A_log  = (const float*)d_in[11];
  const float* Dp     = (const float*)d_in[12];
  const float* out_w  = (const float*)d_in[13];
  const float* fn_w   = (const float*)d_in[14];
  const float* fn_b   = (const float*)d_in[15];
  const float* head_w = (const float*)d_in[16];
  const float* head_b = (const float*)d_in[17];

  float* ws  = (float*)d_ws;
  float*  h      = ws;               //  4,096,000
  float*  xzb    = ws +  4096000;    // 16,384,000 (dt then packed-y in u-half; z-half fp32)
  float*  ub     = ws + 20480000;    //  8,192,000
  float*  xdb    = ws + 28672000;    //  1,280,000
  float*  R      = ws + 29952000;    //  6,553,600 (nb packed / sum / final fp32 nb)
  float*  pooled = ws + 36505600;    //  4,096
  u32*    inwbf  = (u32*)(ws + 36509696);  // 393,216 packed
  u32*    outwbf = inwbf + 393216;         // 196,608 packed  (ends 37,099,520 floats)
  u32*    nb  = (u32*)R;
  float2* sum = (float2*)R;
  float*  nf  = R;

  k_castw<<<(393216+255)/256, 256, 0, stream>>>(in_w,  inwbf,  393216);
  k_castw<<<(196608+255)/256, 256, 0, stream>>>(out_w, outwbf, 196608);
  k_inproj<<<BLROWS*128/256, 256, 0, stream>>>(x, inp_w, inp_b, h);
  for (int i=0;i<6;i++){
    k_ln_bf    <<<BLROWS/4,  256, 0, stream>>>(h, ln_w + i*128, ln_b + i*128, nb);
    k_mm1      <<<dim3(500,16), 64, 0, stream>>>(nb, inwbf + (long)i*512*128, xzb);
    k_conv     <<<BLROWS,    256, 0, stream>>>(xzb, conv_w + i*1024, conv_b + i*256, ub);
    k_gemm_xdbl<<<BLROWS/32, 256, 0, stream>>>(ub, xp_w + (long)i*40*256,
                                               dtp_w + i*2048, dtp_b + i*256, xdb, xzb);
    k_scan1    <<<NBATCH*4*NC, 64, 0, stream>>>(xzb, ub, xdb, A_log + i*4096, sum);
    k_scan2    <<<512,        256, 0, stream>>>(sum);
    k_scan3    <<<NBATCH*4*NC, 64, 0, stream>>>(xzb, ub, xdb, A_log + i*4096, Dp + i*256, sum);
    k_mm3      <<<dim3(500,4),  64, 0, stream>>>((const u32*)xzb, outwbf + (long)i*128*256, h);
  }
  k_ln  <<<BLROWS/4, 256, 0, stream>>>(h, fn_w, fn_b, nf);
  k_pool<<<NBATCH,   128, 0, stream>>>(nf, pooled);
  k_head<<<NBATCH,   128, 0, stream>>>(pooled, head_w, head_b, (float*)d_out);
}